// Round 10
// baseline (232.400 us; speedup 1.0000x reference)
//
#include <hip/hip_runtime.h>
#include <hip/hip_bf16.h>

typedef __bf16 bf16_t;
typedef __bf16 bf16x4 __attribute__((ext_vector_type(4)));
typedef __bf16 bf16x8 __attribute__((ext_vector_type(8)));
typedef float f32x4 __attribute__((ext_vector_type(4)));
typedef float f32x16 __attribute__((ext_vector_type(16)));

// Problem constants: B=2, C=128, H=W=64 -> S=4096, NTOK=8192, NH=4, HC=32

// ---------------- workspace layout (bytes) ----------------
static constexpr size_t WS_WPK   = 0;                       // 655,360
static constexpr size_t WS_PP    = 655360;                  // 3 x 2,097,152 (qp,kp,vp)
static constexpr size_t WS_VT    = WS_PP + 3ull*2097152;    // 2,097,152
static constexpr size_t WS_OPART = WS_VT + 2097152;         // 8bh x 8sp x 4096 x 32 bf16 = 16,777,216
static constexpr size_t WS_LPART = WS_OPART + 16777216;     // 8x8x4096 f32 = 1,048,576

// ---------------- kernel 1: weight transpose+cast via LDS tiles ----------------
struct WPtrs { const float* w1[5]; const float* w2[5]; };

__global__ __launch_bounds__(256) void prep_weights(WPtrs wp, bf16_t* __restrict__ dst) {
    __shared__ float ts[64][65];
    int bx = blockIdx.x;              // 80 blocks: 5 pairs x (8 w1-tiles + 8 w2-tiles)
    int p = bx >> 4;
    int t = bx & 15;
    const float* src; int sld, dld, r0, c0; bf16_t* d;
    if (t < 8) {  // w1 [128][256] -> w1T [256][128]
        src = wp.w1[p]; sld = 256; dld = 128;
        r0 = (t >> 2) * 64; c0 = (t & 3) * 64;
        d = dst + p * 65536;
    } else {      // w2 [256][128] -> w2T [128][256]
        int tt = t - 8;
        src = wp.w2[p]; sld = 128; dld = 256;
        r0 = (tt >> 1) * 64; c0 = (tt & 1) * 64;
        d = dst + p * 65536 + 32768;
    }
    for (int i = threadIdx.x; i < 4096; i += 256) {
        int r = i >> 6, c = i & 63;
        ts[r][c] = src[(r0 + r) * sld + c0 + c];
    }
    __syncthreads();
    for (int i = threadIdx.x; i < 4096; i += 256) {
        int c = i >> 6, r = i & 63;
        d[(c0 + c) * dld + (r0 + r)] = (bf16_t)ts[r][c];
    }
}

// ---------------- kernel 2: fused transpose+LayerNorm+MLP-pair projection ----------------
struct ProjArgs {
    const float* src[3]; const float* g[3]; const float* bb[3];
    const float* B1[3]; const float* B2[3];
    bf16_t* OUT[3]; bf16_t* VTOUT;
};

__global__ __launch_bounds__(256) void projln_kernel(ProjArgs a, const bf16_t* __restrict__ wpk) {
    __shared__ float xs[16][132];
    __shared__ bf16_t al[16][136];
    __shared__ bf16_t hl[16][264];
    int z = blockIdx.y;
    int m0 = blockIdx.x * 16;
    int b = m0 >> 12, s0 = m0 & 4095;
    int tx = threadIdx.x;
    int w = tx >> 6;
    int lane = tx & 63;
    int quad = lane >> 4;
    int l15 = lane & 15;

    const float* src = a.src[z];
    for (int idx = tx; idx < 2048; idx += 256) {
        int c = idx >> 4, tt = idx & 15;
        xs[tt][c] = src[(b * 128 + c) * 4096 + s0 + tt];
    }
    __syncthreads();

    {
        int t = tx >> 4, j = tx & 15;
        float sum = 0.f, sq = 0.f;
#pragma unroll
        for (int k = 0; k < 8; ++k) { float v = xs[t][j + 16 * k]; sum += v; sq += v * v; }
        sum += __shfl_xor(sum, 1); sq += __shfl_xor(sq, 1);
        sum += __shfl_xor(sum, 2); sq += __shfl_xor(sq, 2);
        sum += __shfl_xor(sum, 4); sq += __shfl_xor(sq, 4);
        sum += __shfl_xor(sum, 8); sq += __shfl_xor(sq, 8);
        float mu = sum * (1.0f / 128.0f);
        float var = sq * (1.0f / 128.0f) - mu * mu;
        float rs = rsqrtf(var + 1e-5f);
        const float* g = a.g[z];
        const float* bb = a.bb[z];
#pragma unroll
        for (int k = 0; k < 8; ++k) {
            int c = j + 16 * k;
            al[t][c] = (bf16_t)((xs[t][c] - mu) * rs * g[c] + bb[c]);
        }
    }
    __syncthreads();

    const bf16_t* w1t = wpk + (size_t)z * 65536;
    const bf16_t* w2t = w1t + 32768;
    bf16x8 af[4];
#pragma unroll
    for (int kt = 0; kt < 4; ++kt) af[kt] = *(const bf16x8*)(&al[l15][kt * 32 + quad * 8]);

#pragma unroll
    for (int sub = 0; sub < 4; ++sub) {
        int n = w * 64 + sub * 16 + l15;
        const bf16_t* wrow = w1t + (size_t)n * 128 + quad * 8;
        f32x4 acc = {0.f, 0.f, 0.f, 0.f};
#pragma unroll
        for (int kt = 0; kt < 4; ++kt) {
            bf16x8 bfrag = *(const bf16x8*)(wrow + kt * 32);
            acc = __builtin_amdgcn_mfma_f32_16x16x32_bf16(af[kt], bfrag, acc, 0, 0, 0);
        }
        float bn = a.B1[z][n];
#pragma unroll
        for (int r = 0; r < 4; ++r) {
            float v = acc[r] + bn;
            v = v > 0.f ? v : 0.01f * v;
            hl[quad * 4 + r][n] = (bf16_t)v;
        }
    }
    __syncthreads();

    bf16x8 hf[8];
#pragma unroll
    for (int kt = 0; kt < 8; ++kt)
        hf[kt] = *(const bf16x8*)(&hl[l15][kt * 32 + quad * 8]);

#pragma unroll
    for (int sub = 0; sub < 2; ++sub) {
        int n = w * 32 + sub * 16 + l15;
        const bf16_t* wrow = w2t + (size_t)n * 256 + quad * 8;
        f32x4 acc = {0.f, 0.f, 0.f, 0.f};
#pragma unroll
        for (int kt = 0; kt < 8; ++kt) {
            bf16x8 bfrag = *(const bf16x8*)(wrow + kt * 32);
            acc = __builtin_amdgcn_mfma_f32_16x16x32_bf16(hf[kt], bfrag, acc, 0, 0, 0);
        }
        float bn = a.B2[z][n];
        float vals[4];
#pragma unroll
        for (int r = 0; r < 4; ++r) vals[r] = acc[r] + bn;
#pragma unroll
        for (int r = 0; r < 4; ++r)
            a.OUT[z][(size_t)(m0 + quad * 4 + r) * 128 + n] = (bf16_t)vals[r];
        if (z == 2) {
            int bh = b * 4 + (n >> 5), d = n & 31;
            bf16x4 tv = {(bf16_t)vals[0], (bf16_t)vals[1], (bf16_t)vals[2], (bf16_t)vals[3]};
            *(bf16x4*)(a.VTOUT + ((size_t)(bh * 32 + d)) * 4096 + s0 + quad * 4) = tv;
        }
    }
}

// ---------------- kernel 3: split-K attention (split=8), pipelined, 64 queries/wave ----------------
// Steady state: loads(it+1) -> exp/PV/lacc for tile it-1 -> QK for tile it. No same-iter deps.
// S^T = K.Q^T with K rows bit-swapped so S^T C-layout == PV B-operand layout (zero shuffles).
// p = exp2(s) directly (bounded scores). l-sums on the MFMA pipe via banded-ones A operands.
// Grid 1024 = 4 blocks/CU = 4 waves/SIMD for latency hiding (VGPR ~60 <= 128 cap).
__global__ __launch_bounds__(256, 4) void attn_kernel(const bf16_t* __restrict__ qp,
                                                      const bf16_t* __restrict__ kp,
                                                      const bf16_t* __restrict__ vt,
                                                      bf16_t* __restrict__ opart,
                                                      float* __restrict__ lpart) {
    int lid = blockIdx.x;               // 1024 = 8 bh x 8 split x 16 qb
    int bh = lid & 7;                   // consecutive blocks -> different XCDs: one head per XCD L2
    int r = lid >> 3;
    int split = r & 7;
    int qb = r >> 3;
    int w = threadIdx.x >> 6;
    int lane = threadIdx.x & 63;
    int l31 = lane & 31;
    int h5 = lane >> 5;
    int b = bh >> 2, h = bh & 3;
    int q0 = qb * 256 + w * 64;         // wave covers queries q0..q0+63

    constexpr float kScale = 0.17677669529663687f * 1.4426950408889634f; // 1/sqrt(32)*log2(e)

    bf16x8 qf[2][2];
#pragma unroll
    for (int s = 0; s < 2; ++s) {
        const bf16_t* qrow = qp + ((size_t)(b * 4096 + q0 + s * 32 + l31)) * 128 + h * 32 + h5 * 8;
        bf16x8 q0r = *(const bf16x8*)(qrow);
        bf16x8 q1r = *(const bf16x8*)(qrow + 16);
#pragma unroll
        for (int j = 0; j < 8; ++j) {
            qf[s][0][j] = (bf16_t)((float)q0r[j] * kScale);
            qf[s][1][j] = (bf16_t)((float)q1r[j] * kScale);
        }
    }

    bf16x8 a_up, a_lo;
    {
        bf16_t one = (bf16_t)1.0f, zer = (bf16_t)0.0f;
#pragma unroll
        for (int j = 0; j < 8; ++j) { a_up[j] = (l31 < 16) ? one : zer; a_lo[j] = (l31 < 16) ? zer : one; }
    }

    int key_m = (l31 & ~12) | ((l31 & 4) << 1) | ((l31 & 8) >> 1);
    const bf16_t* kbase = kp + ((size_t)(b * 4096) + split * 512 + key_m) * 128 + h * 32 + h5 * 8;
    const bf16_t* vbase = vt + ((size_t)(bh * 32) + l31) * 4096 + split * 512 + h5 * 8;

    f32x16 acca = {0.f,0.f,0.f,0.f,0.f,0.f,0.f,0.f,0.f,0.f,0.f,0.f,0.f,0.f,0.f,0.f};
    f32x16 accb = acca, lacc = acca;
    f32x16 zero16 = acca;

    // ---- prologue: tile 0 scores; tile 1 loads in flight ----
    bf16x8 kcur0 = *(const bf16x8*)(kbase);
    bf16x8 kcur1 = *(const bf16x8*)(kbase + 16);
    bf16x8 vuse0 = *(const bf16x8*)(vbase);
    bf16x8 vuse1 = *(const bf16x8*)(vbase + 16);

    f32x16 sca = __builtin_amdgcn_mfma_f32_32x32x16_bf16(kcur0, qf[0][0], zero16, 0, 0, 0);
    sca = __builtin_amdgcn_mfma_f32_32x32x16_bf16(kcur1, qf[0][1], sca, 0, 0, 0);
    f32x16 scb = __builtin_amdgcn_mfma_f32_32x32x16_bf16(kcur0, qf[1][0], zero16, 0, 0, 0);
    scb = __builtin_amdgcn_mfma_f32_32x32x16_bf16(kcur1, qf[1][1], scb, 0, 0, 0);

    bf16x8 kfB0 = *(const bf16x8*)(kbase + 4096);
    bf16x8 kfB1 = *(const bf16x8*)(kbase + 4096 + 16);
    bf16x8 vfB0 = *(const bf16x8*)(vbase + 32);
    bf16x8 vfB1 = *(const bf16x8*)(vbase + 32 + 16);

    for (int it = 1; it < 16; ++it) {
        // prefetch tile it+1 (clamped)
        int nt = (it < 15) ? it + 1 : 15;
        bf16x8 nk0 = *(const bf16x8*)(kbase + (size_t)nt * 4096);
        bf16x8 nk1 = *(const bf16x8*)(kbase + (size_t)nt * 4096 + 16);
        bf16x8 nv0 = *(const bf16x8*)(vbase + nt * 32);
        bf16x8 nv1 = *(const bf16x8*)(vbase + nt * 32 + 16);

        // ---- softmax + PV + l for tile it-1 (sca/scb ready since last iter) ----
        bf16x8 pfa0, pfa1, pfb0, pfb1;
#pragma unroll
        for (int j = 0; j < 8; ++j) {
            pfa0[j] = (bf16_t)__builtin_amdgcn_exp2f(sca[j]);
            pfa1[j] = (bf16_t)__builtin_amdgcn_exp2f(sca[8 + j]);
            pfb0[j] = (bf16_t)__builtin_amdgcn_exp2f(scb[j]);
            pfb1[j] = (bf16_t)__builtin_amdgcn_exp2f(scb[8 + j]);
        }
        lacc = __builtin_amdgcn_mfma_f32_32x32x16_bf16(a_up, pfa0, lacc, 0, 0, 0);
        lacc = __builtin_amdgcn_mfma_f32_32x32x16_bf16(a_up, pfa1, lacc, 0, 0, 0);
        lacc = __builtin_amdgcn_mfma_f32_32x32x16_bf16(a_lo, pfb0, lacc, 0, 0, 0);
        lacc = __builtin_amdgcn_mfma_f32_32x32x16_bf16(a_lo, pfb1, lacc, 0, 0, 0);
        acca = __builtin_amdgcn_mfma_f32_32x32x16_bf16(vuse0, pfa0, acca, 0, 0, 0);
        acca = __builtin_amdgcn_mfma_f32_32x32x16_bf16(vuse1, pfa1, acca, 0, 0, 0);
        accb = __builtin_amdgcn_mfma_f32_32x32x16_bf16(vuse0, pfb0, accb, 0, 0, 0);
        accb = __builtin_amdgcn_mfma_f32_32x32x16_bf16(vuse1, pfb1, accb, 0, 0, 0);

        // ---- QK for tile it (kfB loaded a full iteration ago) ----
        sca = __builtin_amdgcn_mfma_f32_32x32x16_bf16(kfB0, qf[0][0], zero16, 0, 0, 0);
        sca = __builtin_amdgcn_mfma_f32_32x32x16_bf16(kfB1, qf[0][1], sca, 0, 0, 0);
        scb = __builtin_amdgcn_mfma_f32_32x32x16_bf16(kfB0, qf[1][0], zero16, 0, 0, 0);
        scb = __builtin_amdgcn_mfma_f32_32x32x16_bf16(kfB1, qf[1][1], scb, 0, 0, 0);

        vuse0 = vfB0; vuse1 = vfB1;
        kfB0 = nk0; kfB1 = nk1; vfB0 = nv0; vfB1 = nv1;
    }

    // ---- epilogue: tile 15 ----
    {
        bf16x8 pfa0, pfa1, pfb0, pfb1;
#pragma unroll
        for (int j = 0; j < 8; ++j) {
            pfa0[j] = (bf16_t)__builtin_amdgcn_exp2f(sca[j]);
            pfa1[j] = (bf16_t)__builtin_amdgcn_exp2f(sca[8 + j]);
            pfb0[j] = (bf16_t)__builtin_amdgcn_exp2f(scb[j]);
            pfb1[j] = (bf16_t)__builtin_amdgcn_exp2f(scb[8 + j]);
        }
        lacc = __builtin_amdgcn_mfma_f32_32x32x16_bf16(a_up, pfa0, lacc, 0, 0, 0);
        lacc = __builtin_amdgcn_mfma_f32_32x32x16_bf16(a_up, pfa1, lacc, 0, 0, 0);
        lacc = __builtin_amdgcn_mfma_f32_32x32x16_bf16(a_lo, pfb0, lacc, 0, 0, 0);
        lacc = __builtin_amdgcn_mfma_f32_32x32x16_bf16(a_lo, pfb1, lacc, 0, 0, 0);
        acca = __builtin_amdgcn_mfma_f32_32x32x16_bf16(vuse0, pfa0, acca, 0, 0, 0);
        acca = __builtin_amdgcn_mfma_f32_32x32x16_bf16(vuse1, pfa1, acca, 0, 0, 0);
        accb = __builtin_amdgcn_mfma_f32_32x32x16_bf16(vuse0, pfb0, accb, 0, 0, 0);
        accb = __builtin_amdgcn_mfma_f32_32x32x16_bf16(vuse1, pfb1, accb, 0, 0, 0);
    }

    size_t obase0 = ((size_t)(bh * 8 + split) * 4096 + q0 + l31) * 32;
#pragma unroll
    for (int g = 0; g < 4; ++g) {
        bf16x4 ov = {(bf16_t)acca[4*g], (bf16_t)acca[4*g+1], (bf16_t)acca[4*g+2], (bf16_t)acca[4*g+3]};
        *(bf16x4*)(opart + obase0 + 8 * g + 4 * h5) = ov;
    }
    size_t obase1 = obase0 + 32ull * 32;
#pragma unroll
    for (int g = 0; g < 4; ++g) {
        bf16x4 ov = {(bf16_t)accb[4*g], (bf16_t)accb[4*g+1], (bf16_t)accb[4*g+2], (bf16_t)accb[4*g+3]};
        *(bf16x4*)(opart + obase1 + 8 * g + 4 * h5) = ov;
    }
    lpart[(bh * 8 + split) * 4096 + q0 + h5 * 32 + l31] = h5 ? lacc[8] : lacc[0];
}

// ---------------- kernel 4: fused combine + mlp1 + mlp2 + fp32 transposed output ----------------
__global__ __launch_bounds__(256) void mlpf_kernel(const bf16_t* __restrict__ opart,
                                                   const float* __restrict__ lpart,
                                                   const bf16_t* __restrict__ wpk,
                                                   const float* __restrict__ b1a,
                                                   const float* __restrict__ b2a,
                                                   const float* __restrict__ b1b,
                                                   const float* __restrict__ b2b,
                                                   const bf16_t* __restrict__ vp,
                                                   float* __restrict__ out) {
    __shared__ bf16_t al[16][136];
    __shared__ bf16_t al2[16][136];
    __shared__ bf16_t hl[16][264];
    int w = threadIdx.x >> 6;
    int lane = threadIdx.x & 63;
    int quad = lane >> 4;
    int l15 = lane & 15;
    int m0 = blockIdx.x * 16;
    int bb = m0 >> 12, s0 = m0 & 4095;

    const bf16_t* w1ta = wpk + 3ull * 65536;
    const bf16_t* w2ta = w1ta + 32768;
    const bf16_t* w1tb = wpk + 4ull * 65536;
    const bf16_t* w2tb = w1tb + 32768;

    // ---- combine split-K partials (split=8) ----
    {
        int t = threadIdx.x >> 4;
        int cg = threadIdx.x & 15;
        int m = m0 + t;
        int qq = m & 4095;
        int h = cg >> 2, d0 = (cg & 3) * 8;
        int bh = bb * 4 + h;
        float accv[8] = {0.f, 0.f, 0.f, 0.f, 0.f, 0.f, 0.f, 0.f};
        float l = 0.f;
#pragma unroll
        for (int s = 0; s < 8; ++s) {
            const bf16_t* op = opart + ((size_t)((bh * 8 + s) * 4096) + qq) * 32 + d0;
            bf16x8 o8 = *(const bf16x8*)op;
#pragma unroll
            for (int j = 0; j < 8; ++j) accv[j] += (float)o8[j];
            l += lpart[(bh * 8 + s) * 4096 + qq];
        }
        float invl = 1.0f / l;
        bf16x8 a8;
#pragma unroll
        for (int j = 0; j < 8; ++j) a8[j] = (bf16_t)(accv[j] * invl);
        *(bf16x8*)(&al[t][cg * 8]) = a8;
    }
    __syncthreads();

    // ---- mlp1 phase 1 ----
    bf16x8 af[4];
#pragma unroll
    for (int kt = 0; kt < 4; ++kt) af[kt] = *(const bf16x8*)(&al[l15][kt * 32 + quad * 8]);
#pragma unroll
    for (int sub = 0; sub < 4; ++sub) {
        int n = w * 64 + sub * 16 + l15;
        const bf16_t* wrow = w1ta + (size_t)n * 128 + quad * 8;
        f32x4 acc = {0.f, 0.f, 0.f, 0.f};
#pragma unroll
        for (int kt = 0; kt < 4; ++kt) {
            bf16x8 bfrag = *(const bf16x8*)(wrow + kt * 32);
            acc = __builtin_amdgcn_mfma_f32_16x16x32_bf16(af[kt], bfrag, acc, 0, 0, 0);
        }
        float bn = b1a[n];
#pragma unroll
        for (int r = 0; r < 4; ++r) {
            float v = acc[r] + bn;
            v = v > 0.f ? v : 0.01f * v;
            hl[quad * 4 + r][n] = (bf16_t)v;
        }
    }
    __syncthreads();

    // ---- mlp1 phase 2 (+vp residual) -> rs1 in LDS ----
    {
        bf16x8 hf[8];
#pragma unroll
        for (int kt = 0; kt < 8; ++kt)
            hf[kt] = *(const bf16x8*)(&hl[l15][kt * 32 + quad * 8]);
#pragma unroll
        for (int sub = 0; sub < 2; ++sub) {
            int n = w * 32 + sub * 16 + l15;
            const bf16_t* wrow = w2ta + (size_t)n * 256 + quad * 8;
            f32x4 acc = {0.f, 0.f, 0.f, 0.f};
#pragma unroll
            for (int kt = 0; kt < 8; ++kt) {
                bf16x8 bfrag = *(const bf16x8*)(wrow + kt * 32);
                acc = __builtin_amdgcn_mfma_f32_16x16x32_bf16(hf[kt], bfrag, acc, 0, 0, 0);
            }
            float bn = b2a[n];
#pragma unroll
            for (int r = 0; r < 4; ++r) {
                int m = m0 + quad * 4 + r;
                float v = acc[r] + bn + (float)vp[(size_t)m * 128 + n];
                al2[quad * 4 + r][n] = (bf16_t)v;
            }
        }
    }
    __syncthreads();

    // ---- mlp2 phase 1 ----
    bf16x8 af2[4];
#pragma unroll
    for (int kt = 0; kt < 4; ++kt) af2[kt] = *(const bf16x8*)(&al2[l15][kt * 32 + quad * 8]);
#pragma unroll
    for (int sub = 0; sub < 4; ++sub) {
        int n = w * 64 + sub * 16 + l15;
        const bf16_t* wrow = w1tb + (size_t)n * 128 + quad * 8;
        f32x4 acc = {0.f, 0.f, 0.f, 0.f};
#pragma unroll
        for (int kt = 0; kt < 4; ++kt) {
            bf16x8 bfrag = *(const bf16x8*)(wrow + kt * 32);
            acc = __builtin_amdgcn_mfma_f32_16x16x32_bf16(af2[kt], bfrag, acc, 0, 0, 0);
        }
        float bn = b1b[n];
#pragma unroll
        for (int r = 0; r < 4; ++r) {
            float v = acc[r] + bn;
            v = v > 0.f ? v : 0.01f * v;
            hl[quad * 4 + r][n] = (bf16_t)v;
        }
    }
    __syncthreads();

    // ---- mlp2 phase 2 (+rs1 residual from LDS) -> fp32 transposed output ----
    {
        bf16x8 hf[8];
#pragma unroll
        for (int kt = 0; kt < 8; ++kt)
            hf[kt] = *(const bf16x8*)(&hl[l15][kt * 32 + quad * 8]);
#pragma unroll
        for (int sub = 0; sub < 2; ++sub) {
            int n = w * 32 + sub * 16 + l15;
            const bf16_t* wrow = w2tb + (size_t)n * 256 + quad * 8;
            f32x4 acc = {0.f, 0.f, 0.f, 0.f};
#pragma unroll
            for (int kt = 0; kt < 8; ++kt) {
                bf16x8 bfrag = *(const bf16x8*)(wrow + kt * 32);
                acc = __builtin_amdgcn_mfma_f32_16x16x32_bf16(hf[kt], bfrag, acc, 0, 0, 0);
            }
            float bn = b2b[n];
            f32x4 ov;
#pragma unroll
            for (int r = 0; r < 4; ++r)
                ov[r] = acc[r] + bn + (float)al2[quad * 4 + r][n];
            *(f32x4*)(out + ((size_t)(bb * 128 + n)) * 4096 + s0 + quad * 4) = ov;
        }
    }
}

// ---------------- launch ----------------
extern "C" void kernel_launch(void* const* d_in, const int* in_sizes, int n_in,
                              void* d_out, int out_size, void* d_ws, size_t ws_size,
                              hipStream_t stream) {
    const float* q = (const float*)d_in[0];
    const float* k = (const float*)d_in[1];
    const float* v = (const float*)d_in[2];
    const float* ln_g[3] = {(const float*)d_in[3], (const float*)d_in[9], (const float*)d_in[15]};
    const float* ln_b[3] = {(const float*)d_in[4], (const float*)d_in[10], (const float*)d_in[16]};
    const float* w1[5] = {(const float*)d_in[5], (const float*)d_in[11], (const float*)d_in[17],
                          (const float*)d_in[21], (const float*)d_in[25]};
    const float* b1[5] = {(const float*)d_in[6], (const float*)d_in[12], (const float*)d_in[18],
                          (const float*)d_in[22], (const float*)d_in[26]};
    const float* w2[5] = {(const float*)d_in[7], (const float*)d_in[13], (const float*)d_in[19],
                          (const float*)d_in[23], (const float*)d_in[27]};
    const float* b2[5] = {(const float*)d_in[8], (const float*)d_in[14], (const float*)d_in[20],
                          (const float*)d_in[24], (const float*)d_in[28]};
    float* out = (float*)d_out;

    char* ws = (char*)d_ws;
    bf16_t* wpk = (bf16_t*)(ws + WS_WPK);
    bf16_t* pp  = (bf16_t*)(ws + WS_PP);
    bf16_t* vtb = (bf16_t*)(ws + WS_VT);
    bf16_t* opart = (bf16_t*)(ws + WS_OPART);
    float* lpart = (float*)(ws + WS_LPART);

    // 1. weight pack
    WPtrs wp;
    for (int p = 0; p < 5; ++p) { wp.w1[p] = w1[p]; wp.w2[p] = w2[p]; }
    prep_weights<<<80, 256, 0, stream>>>(wp, wpk);

    // 2. fused LN + projections; v emits vT
    ProjArgs pa;
    pa.src[0] = q; pa.src[1] = k; pa.src[2] = v;
    for (int i = 0; i < 3; ++i) {
        pa.g[i] = ln_g[i]; pa.bb[i] = ln_b[i];
        pa.B1[i] = b1[i]; pa.B2[i] = b2[i];
        pa.OUT[i] = pp + (size_t)i * 1048576;
    }
    pa.VTOUT = vtb;
    projln_kernel<<<dim3(512, 3), 256, 0, stream>>>(pa, wpk);

    // 3. attention split-K partials (pipelined, split=8, 4 blocks/CU)
    attn_kernel<<<1024, 256, 0, stream>>>(pp, pp + 1048576, vtb, opart, lpart);

    // 4. fused combine + mlp1 + mlp2 + output transpose
    mlpf_kernel<<<512, 256, 0, stream>>>(opart, lpart, wpk,
                                         b1[3], b2[3], b1[4], b2[4],
                                         pp + 2ull * 1048576, out);
}

// Round 11
// 201.639 us; speedup vs baseline: 1.1526x; 1.1526x over previous
//
#include <hip/hip_runtime.h>
#include <hip/hip_bf16.h>

typedef __bf16 bf16_t;
typedef __bf16 bf16x4 __attribute__((ext_vector_type(4)));
typedef __bf16 bf16x8 __attribute__((ext_vector_type(8)));
typedef float f32x4 __attribute__((ext_vector_type(4)));
typedef float f32x16 __attribute__((ext_vector_type(16)));

// Problem constants: B=2, C=128, H=W=64 -> S=4096, NTOK=8192, NH=4, HC=32

// ---------------- workspace layout (bytes) ----------------
static constexpr size_t WS_WPK   = 0;                       // 655,360
static constexpr size_t WS_PP    = 655360;                  // 3 x 2,097,152 (qp,kp,vp)
static constexpr size_t WS_VT    = WS_PP + 3ull*2097152;    // 2,097,152
static constexpr size_t WS_OPART = WS_VT + 2097152;         // 8bh x 4sp x 4096 x 32 bf16 = 8,388,608
static constexpr size_t WS_LPART = WS_OPART + 8388608;      // 8x4x4096 f32 = 524,288

// ---------------- kernel 1: weight transpose+cast via LDS tiles ----------------
struct WPtrs { const float* w1[5]; const float* w2[5]; };

__global__ __launch_bounds__(256) void prep_weights(WPtrs wp, bf16_t* __restrict__ dst) {
    __shared__ float ts[64][65];
    int bx = blockIdx.x;              // 80 blocks: 5 pairs x (8 w1-tiles + 8 w2-tiles)
    int p = bx >> 4;
    int t = bx & 15;
    const float* src; int sld, dld, r0, c0; bf16_t* d;
    if (t < 8) {  // w1 [128][256] -> w1T [256][128]
        src = wp.w1[p]; sld = 256; dld = 128;
        r0 = (t >> 2) * 64; c0 = (t & 3) * 64;
        d = dst + p * 65536;
    } else {      // w2 [256][128] -> w2T [128][256]
        int tt = t - 8;
        src = wp.w2[p]; sld = 128; dld = 256;
        r0 = (tt >> 1) * 64; c0 = (tt & 1) * 64;
        d = dst + p * 65536 + 32768;
    }
    for (int i = threadIdx.x; i < 4096; i += 256) {
        int r = i >> 6, c = i & 63;
        ts[r][c] = src[(r0 + r) * sld + c0 + c];
    }
    __syncthreads();
    for (int i = threadIdx.x; i < 4096; i += 256) {
        int c = i >> 6, r = i & 63;
        d[(c0 + c) * dld + (r0 + r)] = (bf16_t)ts[r][c];
    }
}

// ---------------- kernel 2: fused transpose+LayerNorm+MLP-pair projection ----------------
struct ProjArgs {
    const float* src[3]; const float* g[3]; const float* bb[3];
    const float* B1[3]; const float* B2[3];
    bf16_t* OUT[3]; bf16_t* VTOUT;
};

__global__ __launch_bounds__(256) void projln_kernel(ProjArgs a, const bf16_t* __restrict__ wpk) {
    __shared__ float xs[16][132];
    __shared__ bf16_t al[16][136];
    __shared__ bf16_t hl[16][264];
    int z = blockIdx.y;
    int m0 = blockIdx.x * 16;
    int b = m0 >> 12, s0 = m0 & 4095;
    int tx = threadIdx.x;
    int w = tx >> 6;
    int lane = tx & 63;
    int quad = lane >> 4;
    int l15 = lane & 15;

    const float* src = a.src[z];
    for (int idx = tx; idx < 2048; idx += 256) {
        int c = idx >> 4, tt = idx & 15;
        xs[tt][c] = src[(b * 128 + c) * 4096 + s0 + tt];
    }
    __syncthreads();

    {
        int t = tx >> 4, j = tx & 15;
        float sum = 0.f, sq = 0.f;
#pragma unroll
        for (int k = 0; k < 8; ++k) { float v = xs[t][j + 16 * k]; sum += v; sq += v * v; }
        sum += __shfl_xor(sum, 1); sq += __shfl_xor(sq, 1);
        sum += __shfl_xor(sum, 2); sq += __shfl_xor(sq, 2);
        sum += __shfl_xor(sum, 4); sq += __shfl_xor(sq, 4);
        sum += __shfl_xor(sum, 8); sq += __shfl_xor(sq, 8);
        float mu = sum * (1.0f / 128.0f);
        float var = sq * (1.0f / 128.0f) - mu * mu;
        float rs = rsqrtf(var + 1e-5f);
        const float* g = a.g[z];
        const float* bb = a.bb[z];
#pragma unroll
        for (int k = 0; k < 8; ++k) {
            int c = j + 16 * k;
            al[t][c] = (bf16_t)((xs[t][c] - mu) * rs * g[c] + bb[c]);
        }
    }
    __syncthreads();

    const bf16_t* w1t = wpk + (size_t)z * 65536;
    const bf16_t* w2t = w1t + 32768;
    bf16x8 af[4];
#pragma unroll
    for (int kt = 0; kt < 4; ++kt) af[kt] = *(const bf16x8*)(&al[l15][kt * 32 + quad * 8]);

#pragma unroll
    for (int sub = 0; sub < 4; ++sub) {
        int n = w * 64 + sub * 16 + l15;
        const bf16_t* wrow = w1t + (size_t)n * 128 + quad * 8;
        f32x4 acc = {0.f, 0.f, 0.f, 0.f};
#pragma unroll
        for (int kt = 0; kt < 4; ++kt) {
            bf16x8 bfrag = *(const bf16x8*)(wrow + kt * 32);
            acc = __builtin_amdgcn_mfma_f32_16x16x32_bf16(af[kt], bfrag, acc, 0, 0, 0);
        }
        float bn = a.B1[z][n];
#pragma unroll
        for (int r = 0; r < 4; ++r) {
            float v = acc[r] + bn;
            v = v > 0.f ? v : 0.01f * v;
            hl[quad * 4 + r][n] = (bf16_t)v;
        }
    }
    __syncthreads();

    bf16x8 hf[8];
#pragma unroll
    for (int kt = 0; kt < 8; ++kt)
        hf[kt] = *(const bf16x8*)(&hl[l15][kt * 32 + quad * 8]);

#pragma unroll
    for (int sub = 0; sub < 2; ++sub) {
        int n = w * 32 + sub * 16 + l15;
        const bf16_t* wrow = w2t + (size_t)n * 256 + quad * 8;
        f32x4 acc = {0.f, 0.f, 0.f, 0.f};
#pragma unroll
        for (int kt = 0; kt < 8; ++kt) {
            bf16x8 bfrag = *(const bf16x8*)(wrow + kt * 32);
            acc = __builtin_amdgcn_mfma_f32_16x16x32_bf16(hf[kt], bfrag, acc, 0, 0, 0);
        }
        float bn = a.B2[z][n];
        float vals[4];
#pragma unroll
        for (int r = 0; r < 4; ++r) vals[r] = acc[r] + bn;
#pragma unroll
        for (int r = 0; r < 4; ++r)
            a.OUT[z][(size_t)(m0 + quad * 4 + r) * 128 + n] = (bf16_t)vals[r];
        if (z == 2) {
            int bh = b * 4 + (n >> 5), d = n & 31;
            bf16x4 tv = {(bf16_t)vals[0], (bf16_t)vals[1], (bf16_t)vals[2], (bf16_t)vals[3]};
            *(bf16x4*)(a.VTOUT + ((size_t)(bh * 32 + d)) * 4096 + s0 + quad * 4) = tv;
        }
    }
}

// ---------------- kernel 3: split-K attention (split=4), pipelined, 64 queries/wave ----------------
// Steady state: loads(it+1) -> exp/PV/lacc for tile it-1 -> QK for tile it. No same-iter deps.
// S^T = K.Q^T with K rows bit-swapped so S^T C-layout == PV B-operand layout (zero shuffles).
// p = exp2(s) directly (bounded scores). l-sums on the MFMA pipe via banded-ones A operands.
// opart stored in REGISTER ORDER (slot = h5*16 + reg): two contiguous 16B stores per lane,
// dense 64B line per q column; mlpf un-permutes (d = (r&3) + 8*(r>>2) + 4*h5).
__global__ __launch_bounds__(256, 2) void attn_kernel(const bf16_t* __restrict__ qp,
                                                      const bf16_t* __restrict__ kp,
                                                      const bf16_t* __restrict__ vt,
                                                      bf16_t* __restrict__ opart,
                                                      float* __restrict__ lpart) {
    int lid = blockIdx.x;               // 512 = 8 bh x 4 split x 16 qb
    int bh = lid & 7;                   // consecutive blocks -> different XCDs: one head per XCD L2
    int r = lid >> 3;
    int split = r & 3;
    int qb = r >> 2;
    int w = threadIdx.x >> 6;
    int lane = threadIdx.x & 63;
    int l31 = lane & 31;
    int h5 = lane >> 5;
    int b = bh >> 2, h = bh & 3;
    int q0 = qb * 256 + w * 64;         // wave covers queries q0..q0+63

    constexpr float kScale = 0.17677669529663687f * 1.4426950408889634f; // 1/sqrt(32)*log2(e)

    bf16x8 qf[2][2];
#pragma unroll
    for (int s = 0; s < 2; ++s) {
        const bf16_t* qrow = qp + ((size_t)(b * 4096 + q0 + s * 32 + l31)) * 128 + h * 32 + h5 * 8;
        bf16x8 q0r = *(const bf16x8*)(qrow);
        bf16x8 q1r = *(const bf16x8*)(qrow + 16);
#pragma unroll
        for (int j = 0; j < 8; ++j) {
            qf[s][0][j] = (bf16_t)((float)q0r[j] * kScale);
            qf[s][1][j] = (bf16_t)((float)q1r[j] * kScale);
        }
    }

    bf16x8 a_up, a_lo;
    {
        bf16_t one = (bf16_t)1.0f, zer = (bf16_t)0.0f;
#pragma unroll
        for (int j = 0; j < 8; ++j) { a_up[j] = (l31 < 16) ? one : zer; a_lo[j] = (l31 < 16) ? zer : one; }
    }

    int key_m = (l31 & ~12) | ((l31 & 4) << 1) | ((l31 & 8) >> 1);
    const bf16_t* kbase = kp + ((size_t)(b * 4096) + split * 1024 + key_m) * 128 + h * 32 + h5 * 8;
    const bf16_t* vbase = vt + ((size_t)(bh * 32) + l31) * 4096 + split * 1024 + h5 * 8;

    f32x16 acca = {0.f,0.f,0.f,0.f,0.f,0.f,0.f,0.f,0.f,0.f,0.f,0.f,0.f,0.f,0.f,0.f};
    f32x16 accb = acca, lacc = acca;
    f32x16 zero16 = acca;

    // ---- prologue: tile 0 scores; tile 1 loads in flight ----
    bf16x8 kcur0 = *(const bf16x8*)(kbase);
    bf16x8 kcur1 = *(const bf16x8*)(kbase + 16);
    bf16x8 vuse0 = *(const bf16x8*)(vbase);
    bf16x8 vuse1 = *(const bf16x8*)(vbase + 16);

    f32x16 sca = __builtin_amdgcn_mfma_f32_32x32x16_bf16(kcur0, qf[0][0], zero16, 0, 0, 0);
    sca = __builtin_amdgcn_mfma_f32_32x32x16_bf16(kcur1, qf[0][1], sca, 0, 0, 0);
    f32x16 scb = __builtin_amdgcn_mfma_f32_32x32x16_bf16(kcur0, qf[1][0], zero16, 0, 0, 0);
    scb = __builtin_amdgcn_mfma_f32_32x32x16_bf16(kcur1, qf[1][1], scb, 0, 0, 0);

    bf16x8 kfB0 = *(const bf16x8*)(kbase + 4096);
    bf16x8 kfB1 = *(const bf16x8*)(kbase + 4096 + 16);
    bf16x8 vfB0 = *(const bf16x8*)(vbase + 32);
    bf16x8 vfB1 = *(const bf16x8*)(vbase + 32 + 16);

    for (int it = 1; it < 32; ++it) {
        // prefetch tile it+1 (clamped)
        int nt = (it < 31) ? it + 1 : 31;
        bf16x8 nk0 = *(const bf16x8*)(kbase + (size_t)nt * 4096);
        bf16x8 nk1 = *(const bf16x8*)(kbase + (size_t)nt * 4096 + 16);
        bf16x8 nv0 = *(const bf16x8*)(vbase + nt * 32);
        bf16x8 nv1 = *(const bf16x8*)(vbase + nt * 32 + 16);

        // ---- softmax + PV + l for tile it-1 (sca/scb ready since last iter) ----
        bf16x8 pfa0, pfa1, pfb0, pfb1;
#pragma unroll
        for (int j = 0; j < 8; ++j) {
            pfa0[j] = (bf16_t)__builtin_amdgcn_exp2f(sca[j]);
            pfa1[j] = (bf16_t)__builtin_amdgcn_exp2f(sca[8 + j]);
            pfb0[j] = (bf16_t)__builtin_amdgcn_exp2f(scb[j]);
            pfb1[j] = (bf16_t)__builtin_amdgcn_exp2f(scb[8 + j]);
        }
        lacc = __builtin_amdgcn_mfma_f32_32x32x16_bf16(a_up, pfa0, lacc, 0, 0, 0);
        lacc = __builtin_amdgcn_mfma_f32_32x32x16_bf16(a_up, pfa1, lacc, 0, 0, 0);
        lacc = __builtin_amdgcn_mfma_f32_32x32x16_bf16(a_lo, pfb0, lacc, 0, 0, 0);
        lacc = __builtin_amdgcn_mfma_f32_32x32x16_bf16(a_lo, pfb1, lacc, 0, 0, 0);
        acca = __builtin_amdgcn_mfma_f32_32x32x16_bf16(vuse0, pfa0, acca, 0, 0, 0);
        acca = __builtin_amdgcn_mfma_f32_32x32x16_bf16(vuse1, pfa1, acca, 0, 0, 0);
        accb = __builtin_amdgcn_mfma_f32_32x32x16_bf16(vuse0, pfb0, accb, 0, 0, 0);
        accb = __builtin_amdgcn_mfma_f32_32x32x16_bf16(vuse1, pfb1, accb, 0, 0, 0);

        // ---- QK for tile it (kfB loaded a full iteration ago) ----
        sca = __builtin_amdgcn_mfma_f32_32x32x16_bf16(kfB0, qf[0][0], zero16, 0, 0, 0);
        sca = __builtin_amdgcn_mfma_f32_32x32x16_bf16(kfB1, qf[0][1], sca, 0, 0, 0);
        scb = __builtin_amdgcn_mfma_f32_32x32x16_bf16(kfB0, qf[1][0], zero16, 0, 0, 0);
        scb = __builtin_amdgcn_mfma_f32_32x32x16_bf16(kfB1, qf[1][1], scb, 0, 0, 0);

        vuse0 = vfB0; vuse1 = vfB1;
        kfB0 = nk0; kfB1 = nk1; vfB0 = nv0; vfB1 = nv1;
    }

    // ---- epilogue: tile 31 ----
    {
        bf16x8 pfa0, pfa1, pfb0, pfb1;
#pragma unroll
        for (int j = 0; j < 8; ++j) {
            pfa0[j] = (bf16_t)__builtin_amdgcn_exp2f(sca[j]);
            pfa1[j] = (bf16_t)__builtin_amdgcn_exp2f(sca[8 + j]);
            pfb0[j] = (bf16_t)__builtin_amdgcn_exp2f(scb[j]);
            pfb1[j] = (bf16_t)__builtin_amdgcn_exp2f(scb[8 + j]);
        }
        lacc = __builtin_amdgcn_mfma_f32_32x32x16_bf16(a_up, pfa0, lacc, 0, 0, 0);
        lacc = __builtin_amdgcn_mfma_f32_32x32x16_bf16(a_up, pfa1, lacc, 0, 0, 0);
        lacc = __builtin_amdgcn_mfma_f32_32x32x16_bf16(a_lo, pfb0, lacc, 0, 0, 0);
        lacc = __builtin_amdgcn_mfma_f32_32x32x16_bf16(a_lo, pfb1, lacc, 0, 0, 0);
        acca = __builtin_amdgcn_mfma_f32_32x32x16_bf16(vuse0, pfa0, acca, 0, 0, 0);
        acca = __builtin_amdgcn_mfma_f32_32x32x16_bf16(vuse1, pfa1, acca, 0, 0, 0);
        accb = __builtin_amdgcn_mfma_f32_32x32x16_bf16(vuse0, pfb0, accb, 0, 0, 0);
        accb = __builtin_amdgcn_mfma_f32_32x32x16_bf16(vuse1, pfb1, accb, 0, 0, 0);
    }

    // ---- store partials in register-order layout: slot = h5*16 + reg ----
    {
        size_t obase0 = ((size_t)(bh * 4 + split) * 4096 + q0 + l31) * 32 + h5 * 16;
        bf16x8 oa0, oa1;
#pragma unroll
        for (int j = 0; j < 8; ++j) { oa0[j] = (bf16_t)acca[j]; oa1[j] = (bf16_t)acca[8 + j]; }
        *(bf16x8*)(opart + obase0) = oa0;
        *(bf16x8*)(opart + obase0 + 8) = oa1;
        size_t obase1 = obase0 + 32ull * 32;
        bf16x8 ob0, ob1;
#pragma unroll
        for (int j = 0; j < 8; ++j) { ob0[j] = (bf16_t)accb[j]; ob1[j] = (bf16_t)accb[8 + j]; }
        *(bf16x8*)(opart + obase1) = ob0;
        *(bf16x8*)(opart + obase1 + 8) = ob1;
    }
    lpart[(bh * 4 + split) * 4096 + q0 + h5 * 32 + l31] = h5 ? lacc[8] : lacc[0];
}

// ---------------- kernel 4: fused combine + mlp1 + mlp2 + fp32 transposed output ----------------
__global__ __launch_bounds__(256) void mlpf_kernel(const bf16_t* __restrict__ opart,
                                                   const float* __restrict__ lpart,
                                                   const bf16_t* __restrict__ wpk,
                                                   const float* __restrict__ b1a,
                                                   const float* __restrict__ b2a,
                                                   const float* __restrict__ b1b,
                                                   const float* __restrict__ b2b,
                                                   const bf16_t* __restrict__ vp,
                                                   float* __restrict__ out) {
    __shared__ bf16_t al[16][136];
    __shared__ bf16_t al2[16][136];
    __shared__ bf16_t hl[16][264];
    int w = threadIdx.x >> 6;
    int lane = threadIdx.x & 63;
    int quad = lane >> 4;
    int l15 = lane & 15;
    int m0 = blockIdx.x * 16;
    int bb = m0 >> 12, s0 = m0 & 4095;

    const bf16_t* w1ta = wpk + 3ull * 65536;
    const bf16_t* w2ta = w1ta + 32768;
    const bf16_t* w1tb = wpk + 4ull * 65536;
    const bf16_t* w2tb = w1tb + 32768;

    // ---- combine split-K partials (split=4); opart is in register-order layout ----
    {
        int t = threadIdx.x >> 4;
        int cg = threadIdx.x & 15;
        int m = m0 + t;
        int qq = m & 4095;
        int h = cg >> 2;
        int slot0 = (cg & 3) * 8;              // 8 slots of the 32-slot q column
        int bh = bb * 4 + h;
        float accv[8] = {0.f, 0.f, 0.f, 0.f, 0.f, 0.f, 0.f, 0.f};
        float l = 0.f;
#pragma unroll
        for (int s = 0; s < 4; ++s) {
            const bf16_t* op = opart + ((size_t)((bh * 4 + s) * 4096) + qq) * 32 + slot0;
            bf16x8 o8 = *(const bf16x8*)op;
#pragma unroll
            for (int j = 0; j < 8; ++j) accv[j] += (float)o8[j];
            l += lpart[(bh * 4 + s) * 4096 + qq];
        }
        float invl = 1.0f / l;
        // un-permute: slot = h5*16 + r, d = (r&3) + 8*(r>>2) + 4*h5; 8 slots -> two d-groups of 4
        int h5p = slot0 >> 4;
        int rr = slot0 & 15;
        int dA = 8 * (rr >> 2) + 4 * h5p;
        bf16x4 xa, xb2;
#pragma unroll
        for (int j = 0; j < 4; ++j) { xa[j] = (bf16_t)(accv[j] * invl); xb2[j] = (bf16_t)(accv[4 + j] * invl); }
        *(bf16x4*)(&al[t][h * 32 + dA]) = xa;
        *(bf16x4*)(&al[t][h * 32 + dA + 8]) = xb2;
    }
    __syncthreads();

    // ---- mlp1 phase 1 ----
    bf16x8 af[4];
#pragma unroll
    for (int kt = 0; kt < 4; ++kt) af[kt] = *(const bf16x8*)(&al[l15][kt * 32 + quad * 8]);
#pragma unroll
    for (int sub = 0; sub < 4; ++sub) {
        int n = w * 64 + sub * 16 + l15;
        const bf16_t* wrow = w1ta + (size_t)n * 128 + quad * 8;
        f32x4 acc = {0.f, 0.f, 0.f, 0.f};
#pragma unroll
        for (int kt = 0; kt < 4; ++kt) {
            bf16x8 bfrag = *(const bf16x8*)(wrow + kt * 32);
            acc = __builtin_amdgcn_mfma_f32_16x16x32_bf16(af[kt], bfrag, acc, 0, 0, 0);
        }
        float bn = b1a[n];
#pragma unroll
        for (int r = 0; r < 4; ++r) {
            float v = acc[r] + bn;
            v = v > 0.f ? v : 0.01f * v;
            hl[quad * 4 + r][n] = (bf16_t)v;
        }
    }
    __syncthreads();

    // ---- mlp1 phase 2 (+vp residual) -> rs1 in LDS ----
    {
        bf16x8 hf[8];
#pragma unroll
        for (int kt = 0; kt < 8; ++kt)
            hf[kt] = *(const bf16x8*)(&hl[l15][kt * 32 + quad * 8]);
#pragma unroll
        for (int sub = 0; sub < 2; ++sub) {
            int n = w * 32 + sub * 16 + l15;
            const bf16_t* wrow = w2ta + (size_t)n * 256 + quad * 8;
            f32x4 acc = {0.f, 0.f, 0.f, 0.f};
#pragma unroll
            for (int kt = 0; kt < 8; ++kt) {
                bf16x8 bfrag = *(const bf16x8*)(wrow + kt * 32);
                acc = __builtin_amdgcn_mfma_f32_16x16x32_bf16(hf[kt], bfrag, acc, 0, 0, 0);
            }
            float bn = b2a[n];
#pragma unroll
            for (int r = 0; r < 4; ++r) {
                int m = m0 + quad * 4 + r;
                float v = acc[r] + bn + (float)vp[(size_t)m * 128 + n];
                al2[quad * 4 + r][n] = (bf16_t)v;
            }
        }
    }
    __syncthreads();

    // ---- mlp2 phase 1 ----
    bf16x8 af2[4];
#pragma unroll
    for (int kt = 0; kt < 4; ++kt) af2[kt] = *(const bf16x8*)(&al2[l15][kt * 32 + quad * 8]);
#pragma unroll
    for (int sub = 0; sub < 4; ++sub) {
        int n = w * 64 + sub * 16 + l15;
        const bf16_t* wrow = w1tb + (size_t)n * 128 + quad * 8;
        f32x4 acc = {0.f, 0.f, 0.f, 0.f};
#pragma unroll
        for (int kt = 0; kt < 4; ++kt) {
            bf16x8 bfrag = *(const bf16x8*)(wrow + kt * 32);
            acc = __builtin_amdgcn_mfma_f32_16x16x32_bf16(af2[kt], bfrag, acc, 0, 0, 0);
        }
        float bn = b1b[n];
#pragma unroll
        for (int r = 0; r < 4; ++r) {
            float v = acc[r] + bn;
            v = v > 0.f ? v : 0.01f * v;
            hl[quad * 4 + r][n] = (bf16_t)v;
        }
    }
    __syncthreads();

    // ---- mlp2 phase 2 (+rs1 residual from LDS) -> fp32 transposed output ----
    {
        bf16x8 hf[8];
#pragma unroll
        for (int kt = 0; kt < 8; ++kt)
            hf[kt] = *(const bf16x8*)(&hl[l15][kt * 32 + quad * 8]);
#pragma unroll
        for (int sub = 0; sub < 2; ++sub) {
            int n = w * 32 + sub * 16 + l15;
            const bf16_t* wrow = w2tb + (size_t)n * 256 + quad * 8;
            f32x4 acc = {0.f, 0.f, 0.f, 0.f};
#pragma unroll
            for (int kt = 0; kt < 8; ++kt) {
                bf16x8 bfrag = *(const bf16x8*)(wrow + kt * 32);
                acc = __builtin_amdgcn_mfma_f32_16x16x32_bf16(hf[kt], bfrag, acc, 0, 0, 0);
            }
            float bn = b2b[n];
            f32x4 ov;
#pragma unroll
            for (int r = 0; r < 4; ++r)
                ov[r] = acc[r] + bn + (float)al2[quad * 4 + r][n];
            *(f32x4*)(out + ((size_t)(bb * 128 + n)) * 4096 + s0 + quad * 4) = ov;
        }
    }
}

// ---------------- launch ----------------
extern "C" void kernel_launch(void* const* d_in, const int* in_sizes, int n_in,
                              void* d_out, int out_size, void* d_ws, size_t ws_size,
                              hipStream_t stream) {
    const float* q = (const float*)d_in[0];
    const float* k = (const float*)d_in[1];
    const float* v = (const float*)d_in[2];
    const float* ln_g[3] = {(const float*)d_in[3], (const float*)d_in[9], (const float*)d_in[15]};
    const float* ln_b[3] = {(const float*)d_in[4], (const float*)d_in[10], (const float*)d_in[16]};
    const float* w1[5] = {(const float*)d_in[5], (const float*)d_in[11], (const float*)d_in[17],
                          (const float*)d_in[21], (const float*)d_in[25]};
    const float* b1[5] = {(const float*)d_in[6], (const float*)d_in[12], (const float*)d_in[18],
                          (const float*)d_in[22], (const float*)d_in[26]};
    const float* w2[5] = {(const float*)d_in[7], (const float*)d_in[13], (const float*)d_in[19],
                          (const float*)d_in[23], (const float*)d_in[27]};
    const float* b2[5] = {(const float*)d_in[8], (const float*)d_in[14], (const float*)d_in[20],
                          (const float*)d_in[24], (const float*)d_in[28]};
    float* out = (float*)d_out;

    char* ws = (char*)d_ws;
    bf16_t* wpk = (bf16_t*)(ws + WS_WPK);
    bf16_t* pp  = (bf16_t*)(ws + WS_PP);
    bf16_t* vtb = (bf16_t*)(ws + WS_VT);
    bf16_t* opart = (bf16_t*)(ws + WS_OPART);
    float* lpart = (float*)(ws + WS_LPART);

    // 1. weight pack
    WPtrs wp;
    for (int p = 0; p < 5; ++p) { wp.w1[p] = w1[p]; wp.w2[p] = w2[p]; }
    prep_weights<<<80, 256, 0, stream>>>(wp, wpk);

    // 2. fused LN + projections; v emits vT
    ProjArgs pa;
    pa.src[0] = q; pa.src[1] = k; pa.src[2] = v;
    for (int i = 0; i < 3; ++i) {
        pa.g[i] = ln_g[i]; pa.bb[i] = ln_b[i];
        pa.B1[i] = b1[i]; pa.B2[i] = b2[i];
        pa.OUT[i] = pp + (size_t)i * 1048576;
    }
    pa.VTOUT = vtb;
    projln_kernel<<<dim3(512, 3), 256, 0, stream>>>(pa, wpk);

    // 3. attention split-K partials (pipelined, split=4)
    attn_kernel<<<512, 256, 0, stream>>>(pp, pp + 1048576, vtb, opart, lpart);

    // 4. fused combine + mlp1 + mlp2 + output transpose
    mlpf_kernel<<<512, 256, 0, stream>>>(opart, lpart, wpk,
                                         b1[3], b2[3], b1[4], b2[4],
                                         pp + 2ull * 1048576, out);
}